// Round 6
// baseline (898.928 us; speedup 1.0000x reference)
//
#include <hip/hip_runtime.h>

static constexpr int MM  = 90000;  // cells
static constexpr int TT  = 150;    // steps
static constexpr int BS  = 256;    // threads per block (4 waves)
static constexpr int CPT = 4;      // cells per thread
static constexpr int CPB = BS * CPT;                 // 1024 cells per block
static constexpr int NBR = (MM + CPB - 1) / CPB;     // 88 blocks PER REPLICA
static constexpr int WPB = BS / 64;                  // 4 waves per block
static constexpr int NXCD = 8;                       // replicas (one per XCD)
static constexpr int NLAUNCH = NBR * NXCD;           // 704 blocks launched
static constexpr int PG32 = 512;                     // 2KB u32 flag page per block
static constexpr int PG64 = 1024;                    // 8KB u64 halo page per block
static constexpr int GUARD_MAX = 1 << 16;            // spin cap -> fast-fail, not hang

typedef unsigned int u32x2 __attribute__((ext_vector_type(2)));

// Per-replica flag state; replica r touches only [r] -> flag lines live in r's XCD L2.
// All flags are per-step slots, never reused => value-is-flag is MONOTONE: a reader
// sees either 0 (not yet) or the true value. Coherence failure == stall, never corruption.
__device__ __attribute__((aligned(128))) unsigned int       g_bmax[NXCD][128][PG32]; // [r][slot][t] block max
__device__ __attribute__((aligned(128))) unsigned int       g_res [NXCD][128][PG32]; // [r][slot][t] smax result
__device__ __attribute__((aligned(128))) unsigned long long g_edge[NXCD][NBR][PG64]; // [r][b][t*4+side*2+{AQ,F}]
__device__ int          g_cnt[NXCD];       // replica slot counters (device-scope atomics)
__device__ unsigned int g_done;            // any-replica-finished rescue flag (sc1)

__device__ __forceinline__ float softplus_f(float x) {
    return fmaxf(x, 0.0f) + log1pf(expf(-fabsf(x)));
}
__device__ __forceinline__ unsigned long long packAQ(float A, float Q) {
    return ((unsigned long long)__float_as_uint(Q) << 32) | (unsigned long long)__float_as_uint(A);
}

// Dual-publish: plain store (dirty in local L2 -> local atomic readers see it fast)
// then sc1 store (write-through to IF -> sc1 fallback readers guaranteed current).
#define DSTORE32(p, v) asm volatile("global_store_dword %0, %1, off\n\t"            \
                                    "global_store_dword %0, %1, off sc1"            \
                                    :: "v"(p), "v"(v) : "memory")
#define DSTORE64(p, v) asm volatile("global_store_dwordx2 %0, %1, off\n\t"          \
                                    "global_store_dwordx2 %0, %1, off sc1"          \
                                    :: "v"(p), "v"(v) : "memory")
// sc1 fallback loads (R1-proven shape: fused vmcnt(0))
#define SLD32(d, p) asm volatile("global_load_dword %0, %1, off sc1\n\t"            \
                                 "s_waitcnt vmcnt(0)" : "=&v"(d) : "v"(p) : "memory")
#define SLD64(d, p) asm volatile("global_load_dwordx2 %0, %1, off sc1\n\t"          \
                                 "s_waitcnt vmcnt(0)" : "=&v"(d) : "v"(p) : "memory")
// replica formation / rescue (sc1, proven in R5 -- no hang there)
#define SC1_LD32(d, p) asm volatile("global_load_dword %0, %1, off sc1\n\ts_waitcnt vmcnt(0)" \
                                    : "=v"(d) : "v"(p) : "memory")
#define SC1_ST32(p, v) asm volatile("global_store_dword %0, %1, off sc1\n\ts_waitcnt vmcnt(0)" \
                                    :: "v"(p), "v"(v) : "memory")

#define LOC_ADD32(p, z) __hip_atomic_fetch_add((unsigned int*)(p), (z), \
                            __ATOMIC_RELAXED, __HIP_MEMORY_SCOPE_WORKGROUP)
#define LOC_ADD64(p, z) __hip_atomic_fetch_add((unsigned long long*)(p), (z), \
                            __ATOMIC_RELAXED, __HIP_MEMORY_SCOPE_WORKGROUP)

// 64-lane max reduce in 6 DPP stages; lane 63 ends with the full max. Values >= 0.
#define DPP_MAX(x, ctrl, rm, bm)                                                \
    x = fmaxf(x, __int_as_float(__builtin_amdgcn_update_dpp(                    \
                     0, __float_as_int(x), (ctrl), (rm), (bm), true)))
__device__ __forceinline__ float wave_max64(float x) {
    DPP_MAX(x, 0x111, 0xf, 0xf);   // row_shr:1
    DPP_MAX(x, 0x112, 0xf, 0xf);   // row_shr:2
    DPP_MAX(x, 0x114, 0xf, 0xe);   // row_shr:4
    DPP_MAX(x, 0x118, 0xf, 0xc);   // row_shr:8
    DPP_MAX(x, 0x142, 0xa, 0xf);   // row_bcast:15
    DPP_MAX(x, 0x143, 0xc, 0xf);   // row_bcast:31 -> lane 63 = full max
    return x;
}

__global__ void init_ws_kernel() {
    int i = blockIdx.x * blockDim.x + threadIdx.x;
    int stride = gridDim.x * blockDim.x;
    unsigned int* pb = &g_bmax[0][0][0];
    for (int j = i; j < NXCD * 128 * PG32; j += stride) pb[j] = 0u;
    unsigned int* ps = &g_res[0][0][0];
    for (int j = i; j < NXCD * 128 * PG32; j += stride) ps[j] = 0u;
    unsigned long long* pe = &g_edge[0][0][0];
    for (int j = i; j < NXCD * NBR * PG64; j += stride) pe[j] = 0ull;
    if (i == 0) {
        g_done = 0u;
        for (int r = 0; r < NXCD; ++r) g_cnt[r] = 0;
    }
}

__global__ void __launch_bounds__(BS, 4) sim_kernel(
    const float* __restrict__ Rs,
    const float* __restrict__ sim_dat,
    const float* __restrict__ sdc,
    const float* __restrict__ inflow,
    float* __restrict__ out)
{
    __shared__ float sE[2][WPB][2][3];     // [parity][wave][L/R edge cell][A,Q,F]
    __shared__ float s_redf[TT + 1][WPB];  // per-step per-wave max value-flags (never reused)
    __shared__ float s_inflow[TT];
    __shared__ float s_bc[2];              // [lam, w] relay (wave0 -> all, barrier-ordered)
    __shared__ float s_hL[3], s_hR[3];     // remote halo (A,Q,F)
    __shared__ int   s_panic;
    __shared__ int   s_slot, s_rep, s_go;

    const int tid  = threadIdx.x;
    const int wv   = tid >> 6;
    const int lane = tid & 63;

    // ===== replica formation: ground-truth XCD id + per-XCD slot (R5-proven) =====
    if (tid == 0) {
        unsigned int xcc;
        asm volatile("s_getreg_b32 %0, hwreg(HW_REG_XCC_ID)" : "=s"(xcc));
        const int rep = (int)(xcc & 7u);
        s_rep  = rep;
        s_slot = atomicAdd(&g_cnt[rep], 1);
    }
    __syncthreads();
    const int slot = s_slot;
    const int rep  = s_rep;
    if (slot >= NBR) return;                  // surplus block on this XCD

    if (tid == 0) {                           // pre-gate (R5-proven, no hang)
        int go = 1;
        for (;;) {
            unsigned int c, d;
            SC1_LD32(c, (const unsigned int*)&g_cnt[rep]);
            if ((int)c >= NBR) break;
            SC1_LD32(d, &g_done);
            if (d != 0u) { go = 0; break; }
            __builtin_amdgcn_s_sleep(64);
        }
        s_go = go;
    }
    __syncthreads();
    if (!s_go) return;

    for (int j = tid; j < TT; j += BS) s_inflow[j] = inflow[j];
    for (int j = tid; j < (TT + 1) * WPB; j += BS) (&s_redf[0][0])[j] = 0.0f;
    if (tid == 0) s_panic = 0;
    __syncthreads();

    // opaque zero: defeats LLVM's idempotent-RMW -> load lowering (would re-create R5's L1 bug)
    unsigned int zo_;
    asm volatile("v_mov_b32 %0, 0" : "=v"(zo_));
    const unsigned int       zo   = zo_;
    const unsigned long long zo64 = zo_;

    const int base = slot * CPB + tid * CPT;

    // ---- per-cell constants & initial state (registers all sim) ----
    float A[CPT], Q[CPT], A0v[CPT], bet[CPT], cbv[CPT], k2v[CPT], sq[CPT], FQ[CPT];
    bool  act[CPT];
    #pragma unroll
    for (int c = 0; c < CPT; ++c) {
        int i = base + c;
        act[c] = (i < MM);
        if (act[c]) {
            A[c]   = fmaxf(sim_dat[i], 1e-6f);
            Q[c]   = 0.1f * sim_dat[MM + i];
            A0v[c] = sdc[i] + 0.5f;
            bet[c] = sdc[MM + i] + 1.0f;
        } else { A[c] = 1.0f; Q[c] = 0.0f; A0v[c] = 1.0f; bet[c] = 1.0f; }
        cbv[c] = (0.5f * bet[c]) / 1060.0f;     // (0.5*beta)/RHO  (ref op order)
        k2v[c] = bet[c] / (3180.0f * A0v[c]);   // beta/(3*RHO*A0)
    }
    const bool isStart = (base == 0) | (base == 30000) | (base == 60000);
    const bool isEnd   = (base + 3 == 29999) | (base + 3 == 59999) | (base + 3 == 89999);
    const int midSlot = (base == 15000) ? 0 : (base == 45000) ? 1 : (base == 75000) ? 2 : -1;
    float Rtot = 1.0f;
    if (isEnd) {
        int i3 = base + 3;
        float R1 = sdc[7 * MM + i3] + 0.5f;
        float R2 = sdc[8 * MM + i3] + 0.5f;
        if (i3 == 59999)      { R1 *= softplus_f(Rs[0]); R2 *= softplus_f(Rs[1]); }
        else if (i3 == 89999) { R1 *= softplus_f(Rs[2]); R2 *= softplus_f(Rs[3]); }
        Rtot = R1 + R2;
    }

    const bool pubL = (tid == 0) && (slot > 0);
    const bool pubR = (tid == BS - 1) && (slot < NBR - 1);
    const bool isLeader = (slot == 0);

    // ---- initial derived state + t=0 publishes ----
    float s4 = 0.0f;
    #pragma unroll
    for (int c = 0; c < CPT; ++c) {
        sq[c] = sqrtf(A[c] / A0v[c]);
        float uu = Q[c] / A[c];
        float cc = sqrtf(cbv[c] * sq[c]);
        FQ[c] = Q[c] * uu + k2v[c] * A[c] * sq[c];
        s4 = fmaxf(s4, act[c] ? (fabsf(uu) + cc) : 0.0f);
    }
    if (pubL) { unsigned long long v = packAQ(A[0], Q[0]);
                u32x2 e0 = { (unsigned int)v, (unsigned int)(v >> 32) };
                u32x2 e1 = { __float_as_uint(FQ[0]), 0u };
                DSTORE64(&g_edge[rep][slot][0], e0);
                DSTORE64(&g_edge[rep][slot][1], e1); }
    if (pubR) { unsigned long long v = packAQ(A[3], Q[3]);
                u32x2 e0 = { (unsigned int)v, (unsigned int)(v >> 32) };
                u32x2 e1 = { __float_as_uint(FQ[3]), 0u };
                DSTORE64(&g_edge[rep][slot][2], e0);
                DSTORE64(&g_edge[rep][slot][3], e1); }
    if (lane == 0)       { sE[0][wv][0][0] = A[0]; sE[0][wv][0][1] = Q[0]; sE[0][wv][0][2] = FQ[0]; }
    else if (lane == 63) { sE[0][wv][1][0] = A[3]; sE[0][wv][1][1] = Q[3]; sE[0][wv][1][2] = FQ[3]; }
    {
        float red = wave_max64(s4);
        if (lane == 63) {
            s_redf[0][wv] = red;
            if (wv == 0) {
                volatile float* sf = &s_redf[0][0];
                int g2 = 0; float r1, r2, r3;
                do { r1 = sf[1]; r2 = sf[2]; r3 = sf[3]; ++g2; }
                while ((r1 == 0.0f || r2 == 0.0f || r3 == 0.0f) && g2 < GUARD_MAX);
                float bm = fmaxf(fmaxf(red, r1), fmaxf(r2, r3));
                DSTORE32(&g_bmax[rep][slot][0], __float_as_uint(bm));
            }
        }
    }

    for (int t = 0; t < TT; ++t) {
        const int par = t & 1, npar = par ^ 1;

        // ===== overlap phase (all waves): register-only neighbor exchange =====
        float Am = __shfl_up(A[3], 1, 64),  Qm = __shfl_up(Q[3], 1, 64),  Fm = __shfl_up(FQ[3], 1, 64);
        float Ap = __shfl_down(A[0], 1, 64), Qp = __shfl_down(Q[0], 1, 64), Fp = __shfl_down(FQ[0], 1, 64);

        float dFA[CPT], lapA[CPT], dFQ[CPT], lapQ[CPT];
        #pragma unroll
        for (int c = 0; c < CPT; ++c) {
            float Al = (c == 0) ? Am : A[c-1],  Ql = (c == 0) ? Qm : Q[c-1],  Fl = (c == 0) ? Fm : FQ[c-1];
            float Ar = (c == 3) ? Ap : A[c+1],  Qr = (c == 3) ? Qp : Q[c+1],  Fr = (c == 3) ? Fp : FQ[c+1];
            dFA[c]  = 0.5f * (Qr - Ql);
            lapA[c] = 0.5f * (Ar - 2.0f * A[c] + Al);
            dFQ[c]  = 0.5f * (Fr - Fl);
            lapQ[c] = 0.5f * (Qr - 2.0f * Q[c] + Ql);
        }
        if (midSlot >= 0) out[t * 3 + midSlot] = bet[0] * (sq[0] - 1.0f);
        float qFix = 0.0f;
        if (isStart) qFix = s_inflow[t];
        if (isEnd)   qFix = (bet[3] * (sq[3] - 1.0f)) / Rtot;

        // ===== wave0: leader-tree sync. LOCAL = L2 atomic RMW; every 4th iter = sc1 net =====
        if (wv == 0) {
            const int t4 = t * 4;
            const unsigned int *pA = nullptr, *pB = nullptr;
            const unsigned long long *pC = nullptr;
            bool hasA = false, hasB = false, hasC = false;
            if (isLeader) {
                hasA = true;  pA = &g_bmax[rep][lane][t];              // block words 0..63
                hasB = (lane < NBR - 64);                              // 64..87
                if (hasB) pB = &g_bmax[rep][64 + lane][t];
                if (lane == 24)      { hasC = true; pC = &g_edge[rep][1][t4 + 0]; }  // right nbr L-AQ
                else if (lane == 25) { hasC = true; pC = &g_edge[rep][1][t4 + 1]; }  // right nbr L-F
            } else {
                if (lane == 0) { hasA = true; pA = &g_res[rep][slot][t]; }           // private result slot
                if (lane == 0)                       { hasC = true; pC = &g_edge[rep][slot - 1][t4 + 2]; }
                else if (lane == 1)                  { hasC = true; pC = &g_edge[rep][slot - 1][t4 + 3]; }
                else if (lane == 2 && slot < NBR - 1){ hasC = true; pC = &g_edge[rep][slot + 1][t4 + 0]; }
                else if (lane == 3 && slot < NBR - 1){ hasC = true; pC = &g_edge[rep][slot + 1][t4 + 1]; }
            }
            unsigned int ra = 1u, rb = 1u;
            unsigned long long rc = 1ull;
            int it = 0, guard = 0;
            for (;;) {
                if ((++it & 3) != 0) {                 // local rounds (3 of 4): L2 atomics
                    if (hasA) ra = LOC_ADD32(pA, zo);
                    if (hasB) rb = LOC_ADD32(pB, zo);
                    if (hasC) rc = LOC_ADD64(pC, zo64);
                } else {                               // liveness net: R1-proven sc1 loads
                    if (hasA) SLD32(ra, pA);
                    if (hasB) SLD32(rb, pB);
                    if (hasC) { u32x2 tmp; SLD64(tmp, pC);
                                rc = ((unsigned long long)tmp.y << 32) | tmp.x; }
                }
                if (__all((ra != 0u) & (rb != 0u) & ((unsigned int)rc != 0u))) break;
                if (++guard >= GUARD_MAX) break;
            }
            float smaxv;
            if (isLeader) {
                float vA = __uint_as_float(ra);
                float vB = hasB ? __uint_as_float(rb) : 0.0f;
                float m = wave_max64(fmaxf(vA, vB));
                smaxv = __int_as_float(__builtin_amdgcn_readlane(__float_as_int(m), 63));
                const unsigned int sb = __float_as_uint(smaxv);
                DSTORE32(&g_res[rep][lane][t], sb);                    // broadcast: slots 0..63
                if (lane < NBR - 64) DSTORE32(&g_res[rep][64 + lane][t], sb);  // 64..87
                if (lane == 24)      { s_hR[0] = __uint_as_float((unsigned int)rc);
                                       s_hR[1] = __uint_as_float((unsigned int)(rc >> 32)); }
                else if (lane == 25) { s_hR[2] = __uint_as_float((unsigned int)rc); }
            } else {
                smaxv = __int_as_float(__builtin_amdgcn_readlane((int)ra, 0));
                if (lane == 0)                        { s_hL[0] = __uint_as_float((unsigned int)rc);
                                                        s_hL[1] = __uint_as_float((unsigned int)(rc >> 32)); }
                else if (lane == 1)                   { s_hL[2] = __uint_as_float((unsigned int)rc); }
                else if (lane == 2 && slot < NBR - 1) { s_hR[0] = __uint_as_float((unsigned int)rc);
                                                        s_hR[1] = __uint_as_float((unsigned int)(rc >> 32)); }
                else if (lane == 3 && slot < NBR - 1) { s_hR[2] = __uint_as_float((unsigned int)rc); }
            }
            const float dt  = ((float)(0.9 * 0.001)) / smaxv;   // ref op order
            const float lam = dt / 0.001f;
            const float w   = lam * smaxv;
            if (lane == 0) {
                s_bc[0] = lam; s_bc[1] = w;
                if (guard >= GUARD_MAX) s_panic = 1;
            }
        }
        __syncthreads();   // the ONLY barrier per step (orders s_bc/s_hL/s_hR/sE)
        if (s_panic) break;
        const float lam = s_bc[0];
        const float w   = s_bc[1];

        // ===== per-wave edge fixes =====
        if (lane == 0 && (wv > 0 || slot > 0)) {
            float Al, Ql, Fl;
            if (wv > 0) { Al = sE[par][wv-1][1][0]; Ql = sE[par][wv-1][1][1]; Fl = sE[par][wv-1][1][2]; }
            else        { Al = s_hL[0];             Ql = s_hL[1];             Fl = s_hL[2]; }
            dFA[0]  = 0.5f * (Q[1] - Ql);
            lapA[0] = 0.5f * (A[1] - 2.0f * A[0] + Al);
            dFQ[0]  = 0.5f * (FQ[1] - Fl);
            lapQ[0] = 0.5f * (Q[1] - 2.0f * Q[0] + Ql);
        }
        if (lane == 63 && (wv < WPB - 1 || slot < NBR - 1)) {
            float Ar, Qr, Fr;
            if (wv < WPB - 1) { Ar = sE[par][wv+1][0][0]; Qr = sE[par][wv+1][0][1]; Fr = sE[par][wv+1][0][2]; }
            else              { Ar = s_hR[0];             Qr = s_hR[1];             Fr = s_hR[2]; }
            dFA[3]  = 0.5f * (Qr - Q[2]);
            lapA[3] = 0.5f * (Ar - 2.0f * A[3] + A[2]);
            dFQ[3]  = 0.5f * (Fr - FQ[2]);
            lapQ[3] = 0.5f * (Qr - 2.0f * Q[3] + Q[2]);
        }

        // ===== update + BCs + clamp =====
        #pragma unroll
        for (int c = 0; c < CPT; ++c) {
            int i = base + c;
            if (act[c] && i > 0 && i < MM - 1) {
                A[c] = fmaf(w, lapA[c], fmaf(-lam, dFA[c], A[c]));
                Q[c] = fmaf(w, lapQ[c], fmaf(-lam, dFQ[c], Q[c]));
            }
        }
        if (isStart) Q[0] = qFix;
        if (isEnd)   Q[3] = qFix;
        #pragma unroll
        for (int c = 0; c < CPT; ++c) A[c] = fmaxf(A[c], 1e-6f);

        // publish t+1 edge AQ ASAP (F follows after edge-FQ recompute)
        const int n4 = (t + 1) * 4;
        if (pubL) { unsigned long long v = packAQ(A[0], Q[0]);
                    u32x2 e0 = { (unsigned int)v, (unsigned int)(v >> 32) };
                    DSTORE64(&g_edge[rep][slot][n4 + 0], e0); }
        if (pubR) { unsigned long long v = packAQ(A[3], Q[3]);
                    u32x2 e0 = { (unsigned int)v, (unsigned int)(v >> 32) };
                    DSTORE64(&g_edge[rep][slot][n4 + 2], e0); }

        // ===== derived state for t+1 =====
        float uu[CPT];
        s4 = 0.0f;
        #pragma unroll
        for (int c = 0; c < CPT; ++c) {
            sq[c] = sqrtf(A[c] / A0v[c]);
            uu[c] = Q[c] / A[c];
            float cc = sqrtf(cbv[c] * sq[c]);
            s4 = fmaxf(s4, act[c] ? (fabsf(uu[c]) + cc) : 0.0f);
        }
        FQ[0] = Q[0] * uu[0] + k2v[0] * A[0] * sq[0];
        FQ[3] = Q[3] * uu[3] + k2v[3] * A[3] * sq[3];
        if (pubL) { u32x2 e1 = { __float_as_uint(FQ[0]), 0u };
                    DSTORE64(&g_edge[rep][slot][n4 + 1], e1); }
        if (pubR) { u32x2 e1 = { __float_as_uint(FQ[3]), 0u };
                    DSTORE64(&g_edge[rep][slot][n4 + 3], e1); }
        FQ[1] = Q[1] * uu[1] + k2v[1] * A[1] * sq[1];
        FQ[2] = Q[2] * uu[2] + k2v[2] * A[2] * sq[2];

        {
            float red = wave_max64(s4);
            if (lane == 63) {
                s_redf[t + 1][wv] = red;                 // LDS value-flag (fresh slot)
                if (wv == 0) {
                    volatile float* sf = &s_redf[t + 1][0];
                    int g2 = 0; float r1, r2, r3;
                    do { r1 = sf[1]; r2 = sf[2]; r3 = sf[3]; ++g2; }
                    while ((r1 == 0.0f || r2 == 0.0f || r3 == 0.0f) && g2 < GUARD_MAX);
                    float bm = fmaxf(fmaxf(red, r1), fmaxf(r2, r3));
                    DSTORE32(&g_bmax[rep][slot][t + 1], __float_as_uint(bm));
                }
            }
        }
        // intra-block wave-edge state for t+1 (ordered for readers by next step's barrier)
        if (lane == 0)       { sE[npar][wv][0][0] = A[0]; sE[npar][wv][0][1] = Q[0]; sE[npar][wv][0][2] = FQ[0]; }
        else if (lane == 63) { sE[npar][wv][1][0] = A[3]; sE[npar][wv][1][1] = Q[3]; sE[npar][wv][1][2] = FQ[3]; }
    }

    // any finishing (or panicking) replica releases partial-replica blocks
    if (slot == 0 && tid == 0) SC1_ST32(&g_done, 1u);
}

extern "C" void kernel_launch(void* const* d_in, const int* in_sizes, int n_in,
                              void* d_out, int out_size, void* d_ws, size_t ws_size,
                              hipStream_t stream) {
    (void)in_sizes; (void)n_in; (void)d_ws; (void)ws_size; (void)out_size;

    const float* Rs      = (const float*)d_in[0];
    const float* sim_dat = (const float*)d_in[1];
    const float* sdc     = (const float*)d_in[2];
    const float* inflow  = (const float*)d_in[3];
    float* out = (float*)d_out;

    hipLaunchKernelGGL(init_ws_kernel, dim3(240), dim3(256), 0, stream);

    // 704 blocks (88 per XCD replica) x 4 waves; launch_bounds(256,4) keeps all
    // co-resident (capacity 1024 blocks), so replica formation cannot stall.
    hipLaunchKernelGGL(sim_kernel, dim3(NLAUNCH), dim3(BS), 0, stream,
                       Rs, sim_dat, sdc, inflow, out);
}